// Round 4
// baseline (398.263 us; speedup 1.0000x reference)
//
#include <hip/hip_runtime.h>
#include <hip/hip_bf16.h>

#define VOCAB 50257
#define NB    2048
#define NE    128
#define NCH   393              // ceil(VOCAB/128)
#define NWG   (NCH * (NB/128)) // 6288 = 8 * 786
#define NFIND (NB / 4)         // 512 blocks for find_idx part
#define NTR   ((VOCAB + 63) / 64) // 786 transpose blocks

typedef __bf16 bf16x8 __attribute__((ext_vector_type(8)));
typedef float  f32x4  __attribute__((ext_vector_type(4)));

// ---------------- fused prep: find_idx (blocks 0..511) + transpose (blocks 512..1297) ----------------
__global__ __launch_bounds__(256) void k_prep(const float* __restrict__ oh, int* __restrict__ idx,
                                              const float* __restrict__ w2, __hip_bfloat16* __restrict__ w2T) {
  __shared__ __hip_bfloat16 tile[64][130];
  if (blockIdx.x < NFIND) {
    // ---- find_idx: one wave per row, early exit ----
    const int w    = (blockIdx.x * 256 + threadIdx.x) >> 6;
    const int lane = threadIdx.x & 63;
    const float* row = oh + (long)w * VOCAB;
    const int a = (4 - (w & 3)) & 3;            // first 16B-aligned element of this row
    const f32x4* rp = reinterpret_cast<const f32x4*>(row + a);
    bool done = false;
    for (int i = 0; i < 48; ++i) {
      f32x4 v[4];
#pragma unroll
      for (int j = 0; j < 4; ++j) v[j] = rp[i * 256 + j * 64 + lane];
      bool f = false;
#pragma unroll
      for (int j = 0; j < 4; ++j)
        f |= (v[j][0] != 0.f) | (v[j][1] != 0.f) | (v[j][2] != 0.f) | (v[j][3] != 0.f);
      if (__any(f)) {
#pragma unroll
        for (int j = 0; j < 4; ++j)
#pragma unroll
          for (int k = 0; k < 4; ++k)
            if (v[j][k] != 0.f) idx[w] = a + (i * 256 + j * 64 + lane) * 4 + k;
        done = true;
        break;
      }
    }
    if (!done) {
      if (lane < a && row[lane] != 0.f) idx[w] = lane;
      for (int e = a + 49152 + lane; e < VOCAB; e += 64)
        if (row[e] != 0.f) idx[w] = e;
    }
  } else {
    // ---- transpose: w2 [128][V] f32 -> w2T [V][128] bf16 ----
    const int v0 = (blockIdx.x - NFIND) * 64;
    const int tv = threadIdx.x & 63;
    const int te = threadIdx.x >> 6;   // 0..3
    const int v  = v0 + tv;
#pragma unroll
    for (int e0 = 0; e0 < NE; e0 += 4) {
      int e = e0 + te;
      float val = (v < VOCAB) ? w2[(long)e * VOCAB + v] : 0.f;
      tile[tv][e] = __float2bfloat16(val);
    }
    __syncthreads();
#pragma unroll
    for (int it = 0; it < 16; ++it) {
      int f  = it * 256 + threadIdx.x;
      int r  = f >> 6;
      int c2 = f & 63;
      int vv = v0 + r;
      if (vv < VOCAB) {
        ushort2 p;
        p.x = *reinterpret_cast<const unsigned short*>(&tile[r][2 * c2]);
        p.y = *reinterpret_cast<const unsigned short*>(&tile[r][2 * c2 + 1]);
        reinterpret_cast<ushort2*>(w2T + (long)vv * NE)[c2] = p;
      }
    }
  }
}

// ---------------- kernel 3: z1[b] = bf16(w1[idx[b]]) ----------------
__global__ void k_gather(const float* __restrict__ w1, const int* __restrict__ idx,
                         __hip_bfloat16* __restrict__ z1) {
  int t = blockIdx.x * blockDim.x + threadIdx.x;   // NB*NE threads
  int b = t >> 7, e = t & 127;
  z1[t] = __float2bfloat16(w1[(long)idx[b] * NE + e]);
}

// ---------------- GEMM (operand-swapped): acc[vi][ri] = w2T-frag x z1-frag ----------------
// D layout: z-row = l15, vocab col = lhi*4 + reg. Lane holds 4 consecutive cols of one row per acc reg.
template <bool LSE_PASS>
__global__ __launch_bounds__(256) void k_gemm(
    const __hip_bfloat16* __restrict__ z1,
    const __hip_bfloat16* __restrict__ w2T,
    const float* __restrict__ lse,
    float* __restrict__ pmax, float* __restrict__ psum,
    float* __restrict__ out) {
  // XCD-chunked swizzle: bid%8 = XCD; contiguous chunk-major slice per XCD (6288 = 8*786).
  const int bid = blockIdx.x;
  const int g = (bid & 7) * (NWG / 8) + (bid >> 3);
  const int chunk = g >> 4;          // 0..392 vocab 128-col chunk
  const int rowg  = g & 15;          // 0..15  batch 128-row group
  const int lane = threadIdx.x & 63;
  const int wave = threadIdx.x >> 6;
  const int wm = wave >> 1, wn = wave & 1;
  const int l15 = lane & 15, lhi = lane >> 4;
  const int row0 = rowg * 128 + wm * 64;
  const int col0 = chunk * 128 + wn * 64;

  bf16x8 bz[4][4];
  {
    const __hip_bfloat16* zp = z1 + (row0 + l15) * NE + lhi * 8;
#pragma unroll
    for (int ri = 0; ri < 4; ++ri)
#pragma unroll
      for (int kb = 0; kb < 4; ++kb)
        bz[ri][kb] = *reinterpret_cast<const bf16x8*>(zp + ri * 16 * NE + kb * 32);
  }

  f32x4 acc[4][4];   // [vi][ri]
#pragma unroll
  for (int vi = 0; vi < 4; ++vi)
#pragma unroll
    for (int ri = 0; ri < 4; ++ri)
      acc[vi][ri] = (f32x4){0.f, 0.f, 0.f, 0.f};

#pragma unroll
  for (int vi = 0; vi < 4; ++vi) {
    int col  = col0 + vi * 16 + l15;
    int colc = col < VOCAB ? col : VOCAB - 1;   // clamped dup, masked in epilogue
    const __hip_bfloat16* wp = w2T + colc * NE + lhi * 8;
    bf16x8 aw[4];
#pragma unroll
    for (int kb = 0; kb < 4; ++kb)
      aw[kb] = *reinterpret_cast<const bf16x8*>(wp + kb * 32);
#pragma unroll
    for (int ri = 0; ri < 4; ++ri)
#pragma unroll
      for (int kb = 0; kb < 4; ++kb)
        acc[vi][ri] = __builtin_amdgcn_mfma_f32_16x16x32_bf16(aw[kb], bz[ri][kb], acc[vi][ri], 0, 0, 0);
  }

  if constexpr (LSE_PASS) {
    __shared__ float sm[2][128];
    __shared__ float ss[2][128];
#pragma unroll
    for (int ri = 0; ri < 4; ++ri) {
      float v[16];
      float m = -INFINITY;
#pragma unroll
      for (int vi = 0; vi < 4; ++vi)
#pragma unroll
        for (int r = 0; r < 4; ++r) {
          int col = col0 + vi * 16 + lhi * 4 + r;
          float x = (col < VOCAB) ? acc[vi][ri][r] : -INFINITY;
          v[vi * 4 + r] = x;
          m = fmaxf(m, x);
        }
      m = fmaxf(m, __shfl_xor(m, 16));
      m = fmaxf(m, __shfl_xor(m, 32));
      float s = 0.f;
#pragma unroll
      for (int t = 0; t < 16; ++t) s += __expf(v[t] - m);
      s += __shfl_xor(s, 16);
      s += __shfl_xor(s, 32);
      if (lhi == 0) {
        int lr = wm * 64 + ri * 16 + l15;
        sm[wn][lr] = m;
        ss[wn][lr] = s;
      }
    }
    __syncthreads();
    if (threadIdx.x < 128) {
      int r = threadIdx.x;
      float m0 = sm[0][r], m1 = sm[1][r];
      float s0 = ss[0][r], s1 = ss[1][r];
      float M = fmaxf(m0, m1);
      float S = s0 * __expf(m0 - M) + s1 * __expf(m1 - M);
      int o = chunk * NB + rowg * 128 + r;
      pmax[o] = M;
      psum[o] = S;
    }
  } else {
    // Quarter-staged epilogue, all global stores 16B-aligned.
    // out row byte offset = 201028*grow ≡ 4*(grow&3) mod 16 -> stage each row
    // shifted by sh=grow&3 (scalar LDS writes), read/store aligned at cols ≡ (4-sh)&3.
    __shared__ float tile[32][132];
    float lsev[4];
#pragma unroll
    for (int ri = 0; ri < 4; ++ri) lsev[ri] = lse[row0 + ri * 16 + l15];

#pragma unroll
    for (int q = 0; q < 4; ++q) {           // 32-row quarters of the 128-row block
      if (wm == (q >> 1)) {
#pragma unroll
        for (int rr = 0; rr < 2; ++rr) {
          int ri   = (q & 1) * 2 + rr;
          int irow = rr * 16 + l15;          // 0..31
          int grow = rowg * 128 + q * 32 + irow;
          int sh   = grow & 3;
#pragma unroll
          for (int vi = 0; vi < 4; ++vi) {
            int cbase = sh + wn * 64 + vi * 16 + lhi * 4;
#pragma unroll
            for (int r = 0; r < 4; ++r)
              tile[irow][cbase + r] = acc[vi][ri][r] - lsev[ri];
          }
        }
      }
      __syncthreads();
      {
        int irow = threadIdx.x >> 3;        // 0..31
        int j    = threadIdx.x & 7;         // 0..7
        int grow = rowg * 128 + q * 32 + irow;
        int sh   = grow & 3;
        int h    = (4 - sh) & 3;            // first out-aligned col
        long obase = (long)grow * VOCAB + chunk * 128;
        if (j == 0)
          for (int c = 0; c < h; ++c)
            out[obase + c] = tile[irow][sh + c];
#pragma unroll
        for (int k = 0; k < 4; ++k) {
          int gcol = h + j * 16 + k * 4;
          int gg   = chunk * 128 + gcol;
          if (gcol + 3 < 128) {
            f32x4 v = *reinterpret_cast<const f32x4*>(&tile[irow][sh + gcol]);
            if (gg + 3 < VOCAB) {
              *reinterpret_cast<f32x4*>(out + obase + gcol) = v;
            } else {
#pragma unroll
              for (int r = 0; r < 4; ++r)
                if (gg + r < VOCAB) out[obase + gcol + r] = v[r];
            }
          } else {
#pragma unroll
            for (int r = 0; r < 4; ++r) {
              int c = gcol + r;
              if (c < 128 && chunk * 128 + c < VOCAB) out[obase + c] = tile[irow][sh + c];
            }
          }
        }
      }
      __syncthreads();
    }
  }
}

// ---------------- two-stage chunk-partial merge -> lse[b] ----------------
__global__ void k_lse_part(const float* __restrict__ pmax, const float* __restrict__ psum,
                           float* __restrict__ m2, float* __restrict__ s2) {
  int b  = blockIdx.x * 256 + threadIdx.x;
  int cg = blockIdx.y;
  int c0 = cg * 50, c1 = (c0 + 50 < NCH) ? c0 + 50 : NCH;
  float M = -INFINITY;
  for (int c = c0; c < c1; ++c) M = fmaxf(M, pmax[c * NB + b]);
  float S = 0.f;
  for (int c = c0; c < c1; ++c) S += psum[c * NB + b] * __expf(pmax[c * NB + b] - M);
  m2[cg * NB + b] = M;
  s2[cg * NB + b] = S;
}

__global__ void k_lse_final(const float* __restrict__ m2, const float* __restrict__ s2,
                            float* __restrict__ lse) {
  int b = blockIdx.x * 256 + threadIdx.x;
  float M = -INFINITY;
#pragma unroll
  for (int g = 0; g < 8; ++g) M = fmaxf(M, m2[g * NB + b]);
  float S = 0.f;
#pragma unroll
  for (int g = 0; g < 8; ++g) S += s2[g * NB + b] * __expf(m2[g * NB + b] - M);
  lse[b] = M + __logf(S);
}

extern "C" void kernel_launch(void* const* d_in, const int* in_sizes, int n_in,
                              void* d_out, int out_size, void* d_ws, size_t ws_size,
                              hipStream_t stream) {
  const float* one_hot = (const float*)d_in[0];
  const float* w1      = (const float*)d_in[1];
  const float* w2      = (const float*)d_in[2];
  float* out = (float*)d_out;

  char* ws = (char*)d_ws;
  int*            idx  = (int*)ws;                       // 8 KB
  __hip_bfloat16* z1   = (__hip_bfloat16*)(ws + 8192);   // 512 KB
  __hip_bfloat16* w2T  = (__hip_bfloat16*)(ws + 532480); // 12.87 MB
  float*          pmax = (float*)(ws + 13398272);        // 3.22 MB
  float*          psum = (float*)(ws + 16617728);        // 3.22 MB
  float*          m2   = (float*)(ws + 19837184);        // 64 KB
  float*          s2   = (float*)(ws + 19902720);        // 64 KB
  float*          lse  = (float*)(ws + 19968256);        // 8 KB

  k_prep<<<NFIND + NTR, 256, 0, stream>>>(one_hot, idx, w2, w2T);
  k_gather<<<NB * NE / 256, 256, 0, stream>>>(w1, idx, z1);
  k_gemm<true><<<NWG, 256, 0, stream>>>(z1, w2T, nullptr, pmax, psum, nullptr);
  k_lse_part<<<dim3(NB / 256, 8), 256, 0, stream>>>(pmax, psum, m2, s2);
  k_lse_final<<<NB / 256, 256, 0, stream>>>(m2, s2, lse);
  k_gemm<false><<<NWG, 256, 0, stream>>>(z1, w2T, lse, nullptr, nullptr, out);
}

// Round 5
// 376.858 us; speedup vs baseline: 1.0568x; 1.0568x over previous
//
#include <hip/hip_runtime.h>
#include <hip/hip_bf16.h>

#define VOCAB 50257
#define NB    2048
#define NE    128
#define NCH   393              // ceil(VOCAB/128)
#define NWG   (NCH * (NB/128)) // 6288 = 8 * 786
#define NFIND (NB / 4)         // 512 blocks for find_idx part
#define NTR   ((VOCAB + 63) / 64) // 786 transpose blocks

typedef __bf16 bf16x8 __attribute__((ext_vector_type(8)));
typedef float  f32x4  __attribute__((ext_vector_type(4)));

// ---------------- fused prep: find_idx (blocks 0..511) + transpose (blocks 512..1297) ----------------
__global__ __launch_bounds__(256) void k_prep(const float* __restrict__ oh, int* __restrict__ idx,
                                              const float* __restrict__ w2, __hip_bfloat16* __restrict__ w2T) {
  __shared__ __hip_bfloat16 tile[64][130];
  if (blockIdx.x < NFIND) {
    // ---- find_idx: one wave per row, early exit ----
    const int w    = (blockIdx.x * 256 + threadIdx.x) >> 6;
    const int lane = threadIdx.x & 63;
    const float* row = oh + (long)w * VOCAB;
    const int a = (4 - (w & 3)) & 3;            // first 16B-aligned element of this row
    const f32x4* rp = reinterpret_cast<const f32x4*>(row + a);
    bool done = false;
    for (int i = 0; i < 48; ++i) {
      f32x4 v[4];
#pragma unroll
      for (int j = 0; j < 4; ++j) v[j] = rp[i * 256 + j * 64 + lane];
      bool f = false;
#pragma unroll
      for (int j = 0; j < 4; ++j)
        f |= (v[j][0] != 0.f) | (v[j][1] != 0.f) | (v[j][2] != 0.f) | (v[j][3] != 0.f);
      if (__any(f)) {
#pragma unroll
        for (int j = 0; j < 4; ++j)
#pragma unroll
          for (int k = 0; k < 4; ++k)
            if (v[j][k] != 0.f) idx[w] = a + (i * 256 + j * 64 + lane) * 4 + k;
        done = true;
        break;
      }
    }
    if (!done) {
      if (lane < a && row[lane] != 0.f) idx[w] = lane;
      for (int e = a + 49152 + lane; e < VOCAB; e += 64)
        if (row[e] != 0.f) idx[w] = e;
    }
  } else {
    // ---- transpose: w2 [128][V] f32 -> w2T [V][128] bf16 ----
    const int v0 = (blockIdx.x - NFIND) * 64;
    const int tv = threadIdx.x & 63;
    const int te = threadIdx.x >> 6;   // 0..3
    const int v  = v0 + tv;
#pragma unroll
    for (int e0 = 0; e0 < NE; e0 += 4) {
      int e = e0 + te;
      float val = (v < VOCAB) ? w2[(long)e * VOCAB + v] : 0.f;
      tile[tv][e] = __float2bfloat16(val);
    }
    __syncthreads();
#pragma unroll
    for (int it = 0; it < 16; ++it) {
      int f  = it * 256 + threadIdx.x;
      int r  = f >> 6;
      int c2 = f & 63;
      int vv = v0 + r;
      if (vv < VOCAB) {
        ushort2 p;
        p.x = *reinterpret_cast<const unsigned short*>(&tile[r][2 * c2]);
        p.y = *reinterpret_cast<const unsigned short*>(&tile[r][2 * c2 + 1]);
        reinterpret_cast<ushort2*>(w2T + (long)vv * NE)[c2] = p;
      }
    }
  }
}

// ---------------- kernel 3: z1[b] = bf16(w1[idx[b]]) ----------------
__global__ void k_gather(const float* __restrict__ w1, const int* __restrict__ idx,
                         __hip_bfloat16* __restrict__ z1) {
  int t = blockIdx.x * blockDim.x + threadIdx.x;   // NB*NE threads
  int b = t >> 7, e = t & 127;
  z1[t] = __float2bfloat16(w1[(long)idx[b] * NE + e]);
}

// ---------------- GEMM (operand-swapped): acc[vi][ri] = w2T-frag x z1-frag ----------------
// D layout: z-row = l15, vocab col = lhi*4 + reg. Lane holds 4 consecutive cols of one row per acc reg.
template <bool LSE_PASS>
__global__ __launch_bounds__(256) void k_gemm(
    const __hip_bfloat16* __restrict__ z1,
    const __hip_bfloat16* __restrict__ w2T,
    const float* __restrict__ lse,
    float* __restrict__ pmax, float* __restrict__ psum,
    float* __restrict__ out) {
  // XCD-chunked swizzle: bid%8 = XCD; contiguous chunk-major slice per XCD (6288 = 8*786).
  const int bid = blockIdx.x;
  const int g = (bid & 7) * (NWG / 8) + (bid >> 3);
  const int chunk = g >> 4;          // 0..392 vocab 128-col chunk
  const int rowg  = g & 15;          // 0..15  batch 128-row group
  const int lane = threadIdx.x & 63;
  const int wave = threadIdx.x >> 6;
  const int wm = wave >> 1, wn = wave & 1;
  const int l15 = lane & 15, lhi = lane >> 4;
  const int row0 = rowg * 128 + wm * 64;
  const int col0 = chunk * 128 + wn * 64;

  bf16x8 bz[4][4];
  {
    const __hip_bfloat16* zp = z1 + (row0 + l15) * NE + lhi * 8;
#pragma unroll
    for (int ri = 0; ri < 4; ++ri)
#pragma unroll
      for (int kb = 0; kb < 4; ++kb)
        bz[ri][kb] = *reinterpret_cast<const bf16x8*>(zp + ri * 16 * NE + kb * 32);
  }

  f32x4 acc[4][4];   // [vi][ri]
#pragma unroll
  for (int vi = 0; vi < 4; ++vi)
#pragma unroll
    for (int ri = 0; ri < 4; ++ri)
      acc[vi][ri] = (f32x4){0.f, 0.f, 0.f, 0.f};

#pragma unroll
  for (int vi = 0; vi < 4; ++vi) {
    int col  = col0 + vi * 16 + l15;
    int colc = col < VOCAB ? col : VOCAB - 1;   // clamped dup, masked in epilogue
    const __hip_bfloat16* wp = w2T + colc * NE + lhi * 8;
    bf16x8 aw[4];
#pragma unroll
    for (int kb = 0; kb < 4; ++kb)
      aw[kb] = *reinterpret_cast<const bf16x8*>(wp + kb * 32);
#pragma unroll
    for (int ri = 0; ri < 4; ++ri)
#pragma unroll
      for (int kb = 0; kb < 4; ++kb)
        acc[vi][ri] = __builtin_amdgcn_mfma_f32_16x16x32_bf16(aw[kb], bz[ri][kb], acc[vi][ri], 0, 0, 0);
  }

  if constexpr (LSE_PASS) {
    __shared__ float sm[2][128];
    __shared__ float ss[2][128];
#pragma unroll
    for (int ri = 0; ri < 4; ++ri) {
      float v[16];
      float m = -INFINITY;
#pragma unroll
      for (int vi = 0; vi < 4; ++vi)
#pragma unroll
        for (int r = 0; r < 4; ++r) {
          int col = col0 + vi * 16 + lhi * 4 + r;
          float x = (col < VOCAB) ? acc[vi][ri][r] : -INFINITY;
          v[vi * 4 + r] = x;
          m = fmaxf(m, x);
        }
      m = fmaxf(m, __shfl_xor(m, 16));
      m = fmaxf(m, __shfl_xor(m, 32));
      float s = 0.f;
#pragma unroll
      for (int t = 0; t < 16; ++t) s += __expf(v[t] - m);
      s += __shfl_xor(s, 16);
      s += __shfl_xor(s, 32);
      if (lhi == 0) {
        int lr = wm * 64 + ri * 16 + l15;
        sm[wn][lr] = m;
        ss[wn][lr] = s;
      }
    }
    __syncthreads();
    if (threadIdx.x < 128) {
      int r = threadIdx.x;
      float m0 = sm[0][r], m1 = sm[1][r];
      float s0 = ss[0][r], s1 = ss[1][r];
      float M = fmaxf(m0, m1);
      float S = s0 * __expf(m0 - M) + s1 * __expf(m1 - M);
      int o = chunk * NB + rowg * 128 + r;
      pmax[o] = M;
      psum[o] = S;
    }
  } else {
    // Barrier-free epilogue: store straight from acc. Lanes lhi=0..3 of a row
    // cover 16 consecutive cols -> 64B runs per row per instruction; L2 combines.
    float lsev[4];
#pragma unroll
    for (int ri = 0; ri < 4; ++ri) lsev[ri] = lse[row0 + ri * 16 + l15];
#pragma unroll
    for (int ri = 0; ri < 4; ++ri) {
      long obase = (long)(row0 + ri * 16 + l15) * VOCAB;
#pragma unroll
      for (int vi = 0; vi < 4; ++vi) {
        int col = col0 + vi * 16 + lhi * 4;
        f32x4 v = acc[vi][ri] - lsev[ri];
        if (col + 3 < VOCAB) {
          *reinterpret_cast<f32x4*>(out + obase + col) = v;
        } else {
#pragma unroll
          for (int r = 0; r < 4; ++r)
            if (col + r < VOCAB) out[obase + col + r] = v[r];
        }
      }
    }
  }
}

// ---------------- two-stage chunk-partial merge -> lse[b] ----------------
__global__ void k_lse_part(const float* __restrict__ pmax, const float* __restrict__ psum,
                           float* __restrict__ m2, float* __restrict__ s2) {
  int b  = blockIdx.x * 256 + threadIdx.x;
  int cg = blockIdx.y;
  int c0 = cg * 50, c1 = (c0 + 50 < NCH) ? c0 + 50 : NCH;
  float M = -INFINITY;
  for (int c = c0; c < c1; ++c) M = fmaxf(M, pmax[c * NB + b]);
  float S = 0.f;
  for (int c = c0; c < c1; ++c) S += psum[c * NB + b] * __expf(pmax[c * NB + b] - M);
  m2[cg * NB + b] = M;
  s2[cg * NB + b] = S;
}

__global__ void k_lse_final(const float* __restrict__ m2, const float* __restrict__ s2,
                            float* __restrict__ lse) {
  int b = blockIdx.x * 256 + threadIdx.x;
  float M = -INFINITY;
#pragma unroll
  for (int g = 0; g < 8; ++g) M = fmaxf(M, m2[g * NB + b]);
  float S = 0.f;
#pragma unroll
  for (int g = 0; g < 8; ++g) S += s2[g * NB + b] * __expf(m2[g * NB + b] - M);
  lse[b] = M + __logf(S);
}

extern "C" void kernel_launch(void* const* d_in, const int* in_sizes, int n_in,
                              void* d_out, int out_size, void* d_ws, size_t ws_size,
                              hipStream_t stream) {
  const float* one_hot = (const float*)d_in[0];
  const float* w1      = (const float*)d_in[1];
  const float* w2      = (const float*)d_in[2];
  float* out = (float*)d_out;

  char* ws = (char*)d_ws;
  int*            idx  = (int*)ws;                       // 8 KB
  __hip_bfloat16* z1   = (__hip_bfloat16*)(ws + 8192);   // 512 KB
  __hip_bfloat16* w2T  = (__hip_bfloat16*)(ws + 532480); // 12.87 MB
  float*          pmax = (float*)(ws + 13398272);        // 3.22 MB
  float*          psum = (float*)(ws + 16617728);        // 3.22 MB
  float*          m2   = (float*)(ws + 19837184);        // 64 KB
  float*          s2   = (float*)(ws + 19902720);        // 64 KB
  float*          lse  = (float*)(ws + 19968256);        // 8 KB

  k_prep<<<NFIND + NTR, 256, 0, stream>>>(one_hot, idx, w2, w2T);
  k_gather<<<NB * NE / 256, 256, 0, stream>>>(w1, idx, z1);
  k_gemm<true><<<NWG, 256, 0, stream>>>(z1, w2T, nullptr, pmax, psum, nullptr);
  k_lse_part<<<dim3(NB / 256, 8), 256, 0, stream>>>(pmax, psum, m2, s2);
  k_lse_final<<<NB / 256, 256, 0, stream>>>(m2, s2, lse);
  k_gemm<false><<<NWG, 256, 0, stream>>>(z1, w2T, lse, nullptr, nullptr, out);
}

// Round 6
// 371.660 us; speedup vs baseline: 1.0716x; 1.0140x over previous
//
#include <hip/hip_runtime.h>
#include <hip/hip_bf16.h>

#define VOCAB 50257
#define NB    2048
#define NE    128
#define NCH   393              // ceil(VOCAB/128)  (LSE pass chunking)
#define NWG   (NCH * (NB/128)) // 6288 = 8 * 786
#define NFIND (NB / 4)         // 512 find blocks
#define NTR   ((VOCAB + 63) / 64) // 786 transpose blocks
#define OCH   99               // ceil(VOCAB/512)  (OUT pass chunking)
#define ORG   (NB / 32)        // 64 row groups
#define ONWG  (OCH * ORG)      // 6336 = 8 * 792

typedef __bf16 bf16x8 __attribute__((ext_vector_type(8)));
typedef float  f32x4  __attribute__((ext_vector_type(4)));

// ---------------- fused prep: find+gather (blocks 0..511) | transpose (blocks 512..1297) ----------------
__global__ __launch_bounds__(256) void k_prep(const float* __restrict__ oh,
                                              const float* __restrict__ w1,
                                              const float* __restrict__ w2,
                                              __hip_bfloat16* __restrict__ z1,
                                              __hip_bfloat16* __restrict__ w2T) {
  __shared__ __hip_bfloat16 tile[64][130];
  if (blockIdx.x < NFIND) {
    // ---- find: one wave per row, early exit, depth-2 prefetch; then gather w1 row ----
    const int w    = (blockIdx.x * 256 + threadIdx.x) >> 6;
    const int lane = threadIdx.x & 63;
    const float* row = oh + (long)w * VOCAB;
    const int a = (4 - (w & 3)) & 3;            // first 16B-aligned element
    const f32x4* rp = reinterpret_cast<const f32x4*>(row + a);

    int pos = -1;
    f32x4 v[4], nv[4];
#pragma unroll
    for (int j = 0; j < 4; ++j) v[j] = rp[j * 64 + lane];
    bool found = false;
    for (int i = 0; i < 48 && !found; ++i) {
      if (i + 1 < 48) {
#pragma unroll
        for (int j = 0; j < 4; ++j) nv[j] = rp[(i + 1) * 256 + j * 64 + lane];
      }
      bool f = false;
#pragma unroll
      for (int j = 0; j < 4; ++j)
        f |= (v[j][0] != 0.f) | (v[j][1] != 0.f) | (v[j][2] != 0.f) | (v[j][3] != 0.f);
      if (f) {
#pragma unroll
        for (int j = 0; j < 4; ++j)
#pragma unroll
          for (int k = 0; k < 4; ++k)
            if (v[j][k] != 0.f) pos = a + (i * 256 + j * 64 + lane) * 4 + k;
      }
      found = __any(f);
      if (!found) {
#pragma unroll
        for (int j = 0; j < 4; ++j) v[j] = nv[j];
      }
    }
    if (!found) {
      if (lane < a && row[lane] != 0.f) pos = lane;
      for (int e = a + 49152 + lane; e < VOCAB; e += 64)
        if (row[e] != 0.f) pos = e;
    }
    // wave-wide broadcast of the single found position
#pragma unroll
    for (int off = 1; off < 64; off <<= 1) {
      int o = __shfl_xor(pos, off);
      pos = pos > o ? pos : o;
    }
    // gather: z1[w] = bf16(w1[pos])
    if (pos >= 0) {
      float2 wv = *reinterpret_cast<const float2*>(w1 + (long)pos * NE + lane * 2);
      ushort2 p;
      p.x = (ushort)(__bfloat16_as_ushort(__float2bfloat16(wv.x)));
      p.y = (ushort)(__bfloat16_as_ushort(__float2bfloat16(wv.y)));
      *reinterpret_cast<ushort2*>(z1 + (long)w * NE + lane * 2) = p;
    }
  } else {
    // ---- transpose: w2 [128][V] f32 -> w2T [V][128] bf16 ----
    const int v0 = (blockIdx.x - NFIND) * 64;
    const int tv = threadIdx.x & 63;
    const int te = threadIdx.x >> 6;   // 0..3
    const int v  = v0 + tv;
#pragma unroll
    for (int e0 = 0; e0 < NE; e0 += 4) {
      int e = e0 + te;
      float val = (v < VOCAB) ? w2[(long)e * VOCAB + v] : 0.f;
      tile[tv][e] = __float2bfloat16(val);
    }
    __syncthreads();
#pragma unroll
    for (int it = 0; it < 16; ++it) {
      int f  = it * 256 + threadIdx.x;
      int r  = f >> 6;
      int c2 = f & 63;
      int vv = v0 + r;
      if (vv < VOCAB) {
        ushort2 p;
        p.x = *reinterpret_cast<const unsigned short*>(&tile[r][2 * c2]);
        p.y = *reinterpret_cast<const unsigned short*>(&tile[r][2 * c2 + 1]);
        reinterpret_cast<ushort2*>(w2T + (long)vv * NE)[c2] = p;
      }
    }
  }
}

// ---------------- LSE GEMM (unchanged 128x128 tiles, operand-swapped) ----------------
__global__ __launch_bounds__(256) void k_lsegemm(
    const __hip_bfloat16* __restrict__ z1,
    const __hip_bfloat16* __restrict__ w2T,
    float* __restrict__ pmax, float* __restrict__ psum) {
  const int bid = blockIdx.x;
  const int g = (bid & 7) * (NWG / 8) + (bid >> 3);
  const int chunk = g >> 4;
  const int rowg  = g & 15;
  const int lane = threadIdx.x & 63;
  const int wave = threadIdx.x >> 6;
  const int wm = wave >> 1, wn = wave & 1;
  const int l15 = lane & 15, lhi = lane >> 4;
  const int row0 = rowg * 128 + wm * 64;
  const int col0 = chunk * 128 + wn * 64;

  bf16x8 bz[4][4];
  {
    const __hip_bfloat16* zp = z1 + (row0 + l15) * NE + lhi * 8;
#pragma unroll
    for (int ri = 0; ri < 4; ++ri)
#pragma unroll
      for (int kb = 0; kb < 4; ++kb)
        bz[ri][kb] = *reinterpret_cast<const bf16x8*>(zp + ri * 16 * NE + kb * 32);
  }

  f32x4 acc[4][4];
#pragma unroll
  for (int vi = 0; vi < 4; ++vi)
#pragma unroll
    for (int ri = 0; ri < 4; ++ri)
      acc[vi][ri] = (f32x4){0.f, 0.f, 0.f, 0.f};

#pragma unroll
  for (int vi = 0; vi < 4; ++vi) {
    int col  = col0 + vi * 16 + l15;
    int colc = col < VOCAB ? col : VOCAB - 1;
    const __hip_bfloat16* wp = w2T + colc * NE + lhi * 8;
    bf16x8 aw[4];
#pragma unroll
    for (int kb = 0; kb < 4; ++kb)
      aw[kb] = *reinterpret_cast<const bf16x8*>(wp + kb * 32);
#pragma unroll
    for (int ri = 0; ri < 4; ++ri)
#pragma unroll
      for (int kb = 0; kb < 4; ++kb)
        acc[vi][ri] = __builtin_amdgcn_mfma_f32_16x16x32_bf16(aw[kb], bz[ri][kb], acc[vi][ri], 0, 0, 0);
  }

  __shared__ float sm[2][128];
  __shared__ float ss[2][128];
#pragma unroll
  for (int ri = 0; ri < 4; ++ri) {
    float v[16];
    float m = -INFINITY;
#pragma unroll
    for (int vi = 0; vi < 4; ++vi)
#pragma unroll
      for (int r = 0; r < 4; ++r) {
        int col = col0 + vi * 16 + lhi * 4 + r;
        float x = (col < VOCAB) ? acc[vi][ri][r] : -INFINITY;
        v[vi * 4 + r] = x;
        m = fmaxf(m, x);
      }
    m = fmaxf(m, __shfl_xor(m, 16));
    m = fmaxf(m, __shfl_xor(m, 32));
    float s = 0.f;
#pragma unroll
    for (int t = 0; t < 16; ++t) s += __expf(v[t] - m);
    s += __shfl_xor(s, 16);
    s += __shfl_xor(s, 32);
    if (lhi == 0) {
      int lr = wm * 64 + ri * 16 + l15;
      sm[wn][lr] = m;
      ss[wn][lr] = s;
    }
  }
  __syncthreads();
  if (threadIdx.x < 128) {
    int r = threadIdx.x;
    float m0 = sm[0][r], m1 = sm[1][r];
    float s0 = ss[0][r], s1 = ss[1][r];
    float M = fmaxf(m0, m1);
    float S = s0 * __expf(m0 - M) + s1 * __expf(m1 - M);
    int o = chunk * NB + rowg * 128 + r;
    pmax[o] = M;
    psum[o] = S;
  }
}

// ---------------- two-stage chunk-partial merge -> lse[b] ----------------
__global__ void k_lse_part(const float* __restrict__ pmax, const float* __restrict__ psum,
                           float* __restrict__ m2, float* __restrict__ s2) {
  int b  = blockIdx.x * 256 + threadIdx.x;
  int cg = blockIdx.y;
  int c0 = cg * 50, c1 = (c0 + 50 < NCH) ? c0 + 50 : NCH;
  float M = -INFINITY;
  for (int c = c0; c < c1; ++c) M = fmaxf(M, pmax[c * NB + b]);
  float S = 0.f;
  for (int c = c0; c < c1; ++c) S += psum[c * NB + b] * __expf(pmax[c * NB + b] - M);
  m2[cg * NB + b] = M;
  s2[cg * NB + b] = S;
}

__global__ void k_lse_final(const float* __restrict__ m2, const float* __restrict__ s2,
                            float* __restrict__ lse) {
  int b = blockIdx.x * 256 + threadIdx.x;
  float M = -INFINITY;
#pragma unroll
  for (int g = 0; g < 8; ++g) M = fmaxf(M, m2[g * NB + b]);
  float S = 0.f;
#pragma unroll
  for (int g = 0; g < 8; ++g) S += s2[g * NB + b] * __expf(m2[g * NB + b] - M);
  lse[b] = M + __logf(S);
}

// ---------------- OUT GEMM: 32-row x 512-col flat tiles, direct stores ----------------
// Each block writes 32 contiguous 2KB row-segments (vs 128 x 512B before):
// 4x more bytes per HBM row activation.
__global__ __launch_bounds__(256) void k_out(
    const __hip_bfloat16* __restrict__ z1,
    const __hip_bfloat16* __restrict__ w2T,
    const float* __restrict__ lse,
    float* __restrict__ out) {
  const int bid = blockIdx.x;
  const int g = (bid & 7) * (ONWG / 8) + (bid >> 3);   // XCD chunk-major
  const int chunk = g / ORG;          // 0..98 (512-col chunk)
  const int rowg  = g % ORG;          // 0..63 (32-row group)
  const int lane = threadIdx.x & 63;
  const int wave = threadIdx.x >> 6;  // 0..3 : col quarters
  const int l15 = lane & 15, lhi = lane >> 4;
  const int row0 = rowg * 32;
  const int col0 = chunk * 512 + wave * 128;

  bf16x8 bz[2][4];
  {
    const __hip_bfloat16* zp = z1 + (row0 + l15) * NE + lhi * 8;
#pragma unroll
    for (int ri = 0; ri < 2; ++ri)
#pragma unroll
      for (int kb = 0; kb < 4; ++kb)
        bz[ri][kb] = *reinterpret_cast<const bf16x8*>(zp + ri * 16 * NE + kb * 32);
  }

  f32x4 acc[8][2];
#pragma unroll
  for (int vi = 0; vi < 8; ++vi)
#pragma unroll
    for (int ri = 0; ri < 2; ++ri)
      acc[vi][ri] = (f32x4){0.f, 0.f, 0.f, 0.f};

#pragma unroll
  for (int vi = 0; vi < 8; ++vi) {
    int col  = col0 + vi * 16 + l15;
    int colc = col < VOCAB ? col : VOCAB - 1;
    const __hip_bfloat16* wp = w2T + colc * NE + lhi * 8;
    bf16x8 aw[4];
#pragma unroll
    for (int kb = 0; kb < 4; ++kb)
      aw[kb] = *reinterpret_cast<const bf16x8*>(wp + kb * 32);
#pragma unroll
    for (int ri = 0; ri < 2; ++ri)
#pragma unroll
      for (int kb = 0; kb < 4; ++kb)
        acc[vi][ri] = __builtin_amdgcn_mfma_f32_16x16x32_bf16(aw[kb], bz[ri][kb], acc[vi][ri], 0, 0, 0);
  }

  float lsev[2] = {lse[row0 + l15], lse[row0 + 16 + l15]};
#pragma unroll
  for (int ri = 0; ri < 2; ++ri) {
    long obase = (long)(row0 + ri * 16 + l15) * VOCAB;
#pragma unroll
    for (int vi = 0; vi < 8; ++vi) {       // vi inner: consecutive 64B of same rows
      int col = col0 + vi * 16 + lhi * 4;
      f32x4 v = acc[vi][ri] - lsev[ri];
      if (col + 3 < VOCAB) {
        *reinterpret_cast<f32x4*>(out + obase + col) = v;
      } else {
#pragma unroll
        for (int r = 0; r < 4; ++r)
          if (col + r < VOCAB) out[obase + col + r] = v[r];
      }
    }
  }
}

extern "C" void kernel_launch(void* const* d_in, const int* in_sizes, int n_in,
                              void* d_out, int out_size, void* d_ws, size_t ws_size,
                              hipStream_t stream) {
  const float* one_hot = (const float*)d_in[0];
  const float* w1      = (const float*)d_in[1];
  const float* w2      = (const float*)d_in[2];
  float* out = (float*)d_out;

  char* ws = (char*)d_ws;
  __hip_bfloat16* z1   = (__hip_bfloat16*)(ws + 8192);   // 512 KB
  __hip_bfloat16* w2T  = (__hip_bfloat16*)(ws + 532480); // 12.87 MB
  float*          pmax = (float*)(ws + 13398272);        // 3.22 MB
  float*          psum = (float*)(ws + 16617728);        // 3.22 MB
  float*          m2   = (float*)(ws + 19837184);        // 64 KB
  float*          s2   = (float*)(ws + 19902720);        // 64 KB
  float*          lse  = (float*)(ws + 19968256);        // 8 KB

  k_prep<<<NFIND + NTR, 256, 0, stream>>>(one_hot, w1, w2, z1, w2T);
  k_lsegemm<<<NWG, 256, 0, stream>>>(z1, w2T, pmax, psum);
  k_lse_part<<<dim3(NB / 256, 8), 256, 0, stream>>>(pmax, psum, m2, s2);
  k_lse_final<<<NB / 256, 256, 0, stream>>>(m2, s2, lse);
  k_out<<<ONWG, 256, 0, stream>>>(z1, w2T, lse, out);
}